// Round 7
// baseline (191.006 us; speedup 1.0000x reference)
//
#include <hip/hip_runtime.h>
#include <math.h>

// CAP = (300+400+900)/300/1000*300400 = 1602.13333...; thresh = 0.2*CAP
#define THRESH 320.42666666666668f
#define T_LEN 96
#define SLAB_DAYS 64                 // days per block-iteration (256 thr = 4/day)
#define NBLOCKS 1024                 // persistent grid, 4 blocks/CU

typedef float floatx4 __attribute__((ext_vector_type(4)));

__global__ __launch_bounds__(256) void day_score_kernel(
    const float* __restrict__ pred, const float* __restrict__ tru,
    float* __restrict__ out, int num_days, float scale)
{
    __shared__ float wsum[4];
    const int g = threadIdx.x >> 2;          // day within slab, 0..63
    const int k = threadIdx.x & 3;           // quarter within day, 0..3
    const int n_slabs = (num_days + SLAB_DAYS - 1) / SLAB_DAYS;

    const floatx4* tru4  = (const floatx4*)tru;
    const floatx4* pred4 = (const floatx4*)pred;

    float acc = 0.0f;   // sum of day-scores (each day counted on all 4 lanes)

    for (int slab = blockIdx.x; slab < n_slabs; slab += gridDim.x) {
        const int day = slab * SLAB_DAYS + g;
        if (day >= num_days) break;          // (200000 % 64 == 0: never taken)
        const floatx4* tp = tru4  + (size_t)day * 24 + k * 6;
        const floatx4* pp = pred4 + (size_t)day * 24 + k * 6;

        float s = 0.0f;
#pragma unroll
        for (int j = 0; j < 6; ++j) {
            // nt loads: no-allocate / evict-first in L2+MALL — the test of the
            // "MALL service-port cap" theory. Data is single-use; caching it
            // is pure downside for this kernel.
            const floatx4 tv = __builtin_nontemporal_load(&tp[j]);
            const floatx4 pv = __builtin_nontemporal_load(&pp[j]);
            float r;
            r = (tv.x - pv.x) * __builtin_amdgcn_rcpf(fmaxf(tv.x, THRESH)); s += r * r;
            r = (tv.y - pv.y) * __builtin_amdgcn_rcpf(fmaxf(tv.y, THRESH)); s += r * r;
            r = (tv.z - pv.z) * __builtin_amdgcn_rcpf(fmaxf(tv.z, THRESH)); s += r * r;
            r = (tv.w - pv.w) * __builtin_amdgcn_rcpf(fmaxf(tv.w, THRESH)); s += r * r;
        }
        // combine the 4 quarter-day partials (lanes of a day are 4-aligned)
        s += __shfl_xor(s, 1);
        s += __shfl_xor(s, 2);
        // all 4 lanes hold the full day sum; all accumulate (fixed by x0.25 in scale)
        acc += (1.0f - sqrtf(s * (1.0f / (float)T_LEN))) * 100.0f;
    }

    // wave butterfly: sums all 64 lanes (each day counted 4x -> scale has 0.25)
    acc += __shfl_xor(acc, 1);
    acc += __shfl_xor(acc, 2);
    acc += __shfl_xor(acc, 4);
    acc += __shfl_xor(acc, 8);
    acc += __shfl_xor(acc, 16);
    acc += __shfl_xor(acc, 32);

    const int lane = threadIdx.x & 63;
    const int wave = threadIdx.x >> 6;
    if (lane == 0) wsum[wave] = acc;
    __syncthreads();
    if (threadIdx.x == 0) {
        const float blk = (wsum[0] + wsum[1]) + (wsum[2] + wsum[3]);
        atomicAdd(out, blk * scale);         // NBLOCKS atomics total
    }
}

extern "C" void kernel_launch(void* const* d_in, const int* in_sizes, int n_in,
                              void* d_out, int out_size, void* d_ws, size_t ws_size,
                              hipStream_t stream) {
    (void)n_in; (void)d_ws; (void)ws_size;
    const float* pred = (const float*)d_in[0];   // setup_inputs: {"pred": ..., "true": ...}
    const float* tru  = (const float*)d_in[1];
    float* out = (float*)d_out;

    const int n        = in_sizes[1];
    const int num_days = n / T_LEN;
    const float scale  = 0.25f / (float)num_days;   // 0.25: day counted on 4 lanes

    (void)hipMemsetAsync(out, 0, (size_t)out_size * sizeof(float), stream);
    day_score_kernel<<<NBLOCKS, 256, 0, stream>>>(pred, tru, out, num_days, scale);
}

// Round 9
// 170.535 us; speedup vs baseline: 1.1200x; 1.1200x over previous
//
#include <hip/hip_runtime.h>
#include <math.h>

// CAP = (300+400+900)/300/1000*300400 = 1602.13333...; thresh = 0.2*CAP
#define THRESH 320.42666666666668f
#define T_LEN 96

typedef float floatx4 __attribute__((ext_vector_type(4)));

// 2 threads per day; each thread owns a half-day (48 floats = 12 float4) from
// each input. The loads are issued from inline asm: 12 contiguous dwordx4
// from `true`, then 12 from `pred`, then a single vmcnt(0). The compiler can
// neither reorder, interleave, nor shrink this burst (R2-R4 all had their
// hoisted loads silently re-sunk; VGPR_Count==32 proved it).
__global__ __launch_bounds__(256) void day_score_kernel(
    const float* __restrict__ pred, const float* __restrict__ tru,
    float* __restrict__ out, int num_days, float scale)
{
    __shared__ float wsum[4];
    const int tid  = blockIdx.x * 256 + threadIdx.x;
    const int day  = tid >> 1;
    const int half = tid & 1;
    const bool valid = (day < num_days);
    const int day_c  = valid ? day : (num_days - 1);

    const float* ta = tru  + (size_t)day_c * T_LEN + half * 48;
    const float* pa = pred + (size_t)day_c * T_LEN + half * 48;

    floatx4 t0,t1,t2,t3,t4,t5,t6,t7,t8,t9,t10,t11;
    floatx4 p0,p1,p2,p3,p4,p5,p6,p7,p8,p9,p10,p11;
    asm volatile(
        "global_load_dwordx4 %0,  %24, off\n\t"
        "global_load_dwordx4 %1,  %24, off offset:16\n\t"
        "global_load_dwordx4 %2,  %24, off offset:32\n\t"
        "global_load_dwordx4 %3,  %24, off offset:48\n\t"
        "global_load_dwordx4 %4,  %24, off offset:64\n\t"
        "global_load_dwordx4 %5,  %24, off offset:80\n\t"
        "global_load_dwordx4 %6,  %24, off offset:96\n\t"
        "global_load_dwordx4 %7,  %24, off offset:112\n\t"
        "global_load_dwordx4 %8,  %24, off offset:128\n\t"
        "global_load_dwordx4 %9,  %24, off offset:144\n\t"
        "global_load_dwordx4 %10, %24, off offset:160\n\t"
        "global_load_dwordx4 %11, %24, off offset:176\n\t"
        "global_load_dwordx4 %12, %25, off\n\t"
        "global_load_dwordx4 %13, %25, off offset:16\n\t"
        "global_load_dwordx4 %14, %25, off offset:32\n\t"
        "global_load_dwordx4 %15, %25, off offset:48\n\t"
        "global_load_dwordx4 %16, %25, off offset:64\n\t"
        "global_load_dwordx4 %17, %25, off offset:80\n\t"
        "global_load_dwordx4 %18, %25, off offset:96\n\t"
        "global_load_dwordx4 %19, %25, off offset:112\n\t"
        "global_load_dwordx4 %20, %25, off offset:128\n\t"
        "global_load_dwordx4 %21, %25, off offset:144\n\t"
        "global_load_dwordx4 %22, %25, off offset:160\n\t"
        "global_load_dwordx4 %23, %25, off offset:176\n\t"
        "s_waitcnt vmcnt(0)"
        : "=&v"(t0), "=&v"(t1), "=&v"(t2),  "=&v"(t3),
          "=&v"(t4), "=&v"(t5), "=&v"(t6),  "=&v"(t7),
          "=&v"(t8), "=&v"(t9), "=&v"(t10), "=&v"(t11),
          "=&v"(p0), "=&v"(p1), "=&v"(p2),  "=&v"(p3),
          "=&v"(p4), "=&v"(p5), "=&v"(p6),  "=&v"(p7),
          "=&v"(p8), "=&v"(p9), "=&v"(p10), "=&v"(p11)
        : "v"(ta), "v"(pa)
        : "memory");

    float s = 0.0f;
#define ACC(tv, pv)                                                               \
    {                                                                             \
        float r;                                                                  \
        r = (tv.x - pv.x) * __builtin_amdgcn_rcpf(fmaxf(tv.x, THRESH)); s += r*r; \
        r = (tv.y - pv.y) * __builtin_amdgcn_rcpf(fmaxf(tv.y, THRESH)); s += r*r; \
        r = (tv.z - pv.z) * __builtin_amdgcn_rcpf(fmaxf(tv.z, THRESH)); s += r*r; \
        r = (tv.w - pv.w) * __builtin_amdgcn_rcpf(fmaxf(tv.w, THRESH)); s += r*r; \
    }
    ACC(t0,p0) ACC(t1,p1) ACC(t2,p2)  ACC(t3,p3)
    ACC(t4,p4) ACC(t5,p5) ACC(t6,p6)  ACC(t7,p7)
    ACC(t8,p8) ACC(t9,p9) ACC(t10,p10) ACC(t11,p11)
#undef ACC

    // combine the two half-day lanes (pairs are lane-aligned)
    s += __shfl_xor(s, 1);
    float score = valid ? (1.0f - sqrtf(s * (1.0f / (float)T_LEN))) * 100.0f : 0.0f;
    // day d sits on lanes 2d,2d+1; butterfly over {2,4,8,16,32} sums one
    // parity class (32 lanes) = each of the wave's 32 days exactly ONCE.
    score += __shfl_xor(score, 2);
    score += __shfl_xor(score, 4);
    score += __shfl_xor(score, 8);
    score += __shfl_xor(score, 16);
    score += __shfl_xor(score, 32);

    const int lane = threadIdx.x & 63;
    const int wave = threadIdx.x >> 6;
    if (lane == 0) wsum[wave] = score;
    __syncthreads();
    if (threadIdx.x == 0) {
        const float blk = (wsum[0] + wsum[1]) + (wsum[2] + wsum[3]);
        atomicAdd(out, blk * scale);
    }
}

extern "C" void kernel_launch(void* const* d_in, const int* in_sizes, int n_in,
                              void* d_out, int out_size, void* d_ws, size_t ws_size,
                              hipStream_t stream) {
    (void)n_in; (void)d_ws; (void)ws_size;
    const float* pred = (const float*)d_in[0];   // setup_inputs: {"pred": ..., "true": ...}
    const float* tru  = (const float*)d_in[1];
    float* out = (float*)d_out;

    const int n        = in_sizes[1];
    const int num_days = n / T_LEN;
    const int nblocks  = (num_days * 2 + 255) / 256;    // 1563 for 200000 days
    const float scale  = 1.0f / (float)num_days;        // each day counted once

    (void)hipMemsetAsync(out, 0, (size_t)out_size * sizeof(float), stream);
    day_score_kernel<<<nblocks, 256, 0, stream>>>(pred, tru, out, num_days, scale);
}